// Round 1
// baseline (126.872 us; speedup 1.0000x reference)
//
#include <hip/hip_runtime.h>
#include <hip/hip_bf16.h>

// AlignmentLoss: loss = -(sum(tril(G,-1)*eq) / (sum(tril(eq,-1)) * ||tril(G,-1)||_F))
// with G = A A^T, A: 4096x1024 fp32, target: 4096 int32 (classes < 1000).
//
// Algebraic reduction (no NxN gram needed):
//   S1 = 0.5*(sum_c ||s_c||^2 - sum_i ||a_i||^2),  s_c = sum of rows with class c
//   S2 = 0.5*(sum_c n_c^2 - N)
//   S3 = 0.5*(||A^T A||_F^2 - sum_i ||a_i||^4)     (since ||AA^T||_F = ||A^T A||_F)
//   loss = -S1 / (S2 * sqrt(S3))

typedef __attribute__((ext_vector_type(8))) short short8;
typedef __attribute__((ext_vector_type(4))) float f32x4;

#define N_ROWS 4096
#define D_DIM  1024
#define N_CLS  1000

__device__ __forceinline__ unsigned short f2bf(float f) {
  unsigned u = __float_as_uint(f);
  u += 0x7fffu + ((u >> 16) & 1u);   // round-to-nearest-even
  return (unsigned short)(u >> 16);
}

// ---------------------------------------------------------------------------
// K1: transpose + convert  A[4096][1024] fp32  ->  At[1024][4096] bf16
// grid (64, 16): blockIdx.x = 64-row tile of A, blockIdx.y = 64-dim tile.
// ---------------------------------------------------------------------------
__global__ void __launch_bounds__(256) ktrans(const float* __restrict__ A,
                                              short* __restrict__ At) {
  __shared__ short tile[64 * 68];       // [d_local][i_local], pitch 68 to dodge conflicts
  const int tid = threadIdx.x;
  const int i0 = blockIdx.x * 64, d0 = blockIdx.y * 64;
  const int c16 = tid & 15, rgrp = tid >> 4;
#pragma unroll
  for (int rr = 0; rr < 4; ++rr) {
    const int row = rgrp + rr * 16;     // i_local 0..63
    const float4 v = *(const float4*)(A + (size_t)(i0 + row) * D_DIM + d0 + c16 * 4);
    tile[(c16 * 4 + 0) * 68 + row] = (short)f2bf(v.x);
    tile[(c16 * 4 + 1) * 68 + row] = (short)f2bf(v.y);
    tile[(c16 * 4 + 2) * 68 + row] = (short)f2bf(v.z);
    tile[(c16 * 4 + 3) * 68 + row] = (short)f2bf(v.w);
  }
  __syncthreads();
  const int wrow = tid >> 2, wc = tid & 3;   // d_local row, 16-short chunk
  short8 s0, s1;
#pragma unroll
  for (int q = 0; q < 8; ++q) {
    s0[q] = tile[wrow * 68 + wc * 16 + q];
    s1[q] = tile[wrow * 68 + wc * 16 + 8 + q];
  }
  short* dst = At + (size_t)(d0 + wrow) * N_ROWS + i0 + wc * 16;
  *(short8*)(dst)     = s0;
  *(short8*)(dst + 8) = s1;
}

// ---------------------------------------------------------------------------
// Krow: per-row r_i = ||a_i||^2; per-wave fp64 partials of sum(r) and sum(r^2).
// grid 64 x 256 threads = 256 waves, 16 rows each.  rowp[2*w] = sum r, [2*w+1] = sum r^2
// ---------------------------------------------------------------------------
__global__ void __launch_bounds__(256) krow(const float* __restrict__ A,
                                            double* __restrict__ rowp) {
  const int tid = threadIdx.x, lane = tid & 63;
  const int w = blockIdx.x * 4 + (tid >> 6);
  double ls = 0.0, lq = 0.0;
  for (int r = 0; r < 16; ++r) {
    const int i = w * 16 + r;
    const float4* p = (const float4*)(A + (size_t)i * D_DIM);
    float s = 0.f;
#pragma unroll
    for (int c = 0; c < 4; ++c) {
      const float4 v = p[lane + c * 64];
      s += v.x * v.x + v.y * v.y + v.z * v.z + v.w * v.w;
    }
#pragma unroll
    for (int off = 32; off; off >>= 1) s += __shfl_down(s, off);
    if (lane == 0) { ls += (double)s; lq += (double)s * (double)s; }
  }
  if (lane == 0) { rowp[2 * w] = ls; rowp[2 * w + 1] = lq; }
}

// ---------------------------------------------------------------------------
// Kclass: block per class. Build LDS list of matching rows, accumulate s_c in
// registers (thread owns 4 dims), emit ||s_c||^2 and n_c.  No global atomics.
// ---------------------------------------------------------------------------
__global__ void __launch_bounds__(256) kclass(const float* __restrict__ A,
                                              const int* __restrict__ target,
                                              double* __restrict__ cssp,
                                              int* __restrict__ cntp) {
  __shared__ int list[N_ROWS];
  __shared__ int lcnt;
  __shared__ float wred[4];
  const int c = blockIdx.x, tid = threadIdx.x;
  if (tid == 0) lcnt = 0;
  __syncthreads();
  for (int j = tid; j < N_ROWS; j += 256)
    if (target[j] == c) { int p = atomicAdd(&lcnt, 1); list[p] = j; }
  __syncthreads();
  const int n = lcnt;
  float4 acc = make_float4(0.f, 0.f, 0.f, 0.f);
  for (int m = 0; m < n; ++m) {
    const float4 v = *(const float4*)(A + (size_t)list[m] * D_DIM + tid * 4);
    acc.x += v.x; acc.y += v.y; acc.z += v.z; acc.w += v.w;
  }
  float s = acc.x * acc.x + acc.y * acc.y + acc.z * acc.z + acc.w * acc.w;
#pragma unroll
  for (int off = 32; off; off >>= 1) s += __shfl_down(s, off);
  const int lane = tid & 63, wid = tid >> 6;
  if (lane == 0) wred[wid] = s;
  __syncthreads();
  if (tid == 0) {
    cssp[c] = (double)(wred[0] + wred[1] + wred[2] + wred[3]);
    cntp[c] = n;
  }
}

// ---------------------------------------------------------------------------
// Kgemm: B = At * At^T (1024x1024, K=4096) in bf16 MFMA, fused ||B||_F^2.
// 128x128 tile, 4 waves (2x2), 16x16x32 MFMA, BK=32.  grid (8,8).
// Frobenius-only epilogue -> insensitive to C-layout row/col transposition.
// ---------------------------------------------------------------------------
__global__ void __launch_bounds__(256) kgemmfrob(const short* __restrict__ At,
                                                 double* __restrict__ frobp) {
  __shared__ __align__(16) short As[128 * 32];
  __shared__ __align__(16) short Bs[128 * 32];
  __shared__ float wred[4];
  const int tid = threadIdx.x;
  const int bx = blockIdx.x, by = blockIdx.y;
  const short* Xa = At + (size_t)(bx * 128) * N_ROWS;
  const short* Xb = At + (size_t)(by * 128) * N_ROWS;
  f32x4 acc[4][4];
#pragma unroll
  for (int m = 0; m < 4; ++m)
#pragma unroll
    for (int n = 0; n < 4; ++n) acc[m][n] = (f32x4){0.f, 0.f, 0.f, 0.f};

  const int lane = tid & 63, wid = tid >> 6;
  const int wr = wid >> 1, wc = wid & 1;
  const int row16 = lane & 15, kofs = (lane >> 4) * 8;

  for (int k0 = 0; k0 < N_ROWS; k0 += 32) {
#pragma unroll
    for (int c = tid; c < 512; c += 256) {
      const int row = c >> 2, col = (c & 3) * 8;
      *(short8*)&As[row * 32 + col] = *(const short8*)&Xa[(size_t)row * N_ROWS + k0 + col];
      *(short8*)&Bs[row * 32 + col] = *(const short8*)&Xb[(size_t)row * N_ROWS + k0 + col];
    }
    __syncthreads();
    short8 af[4], bf[4];
#pragma unroll
    for (int m = 0; m < 4; ++m)
      af[m] = *(const short8*)&As[(wr * 64 + m * 16 + row16) * 32 + kofs];
#pragma unroll
    for (int n = 0; n < 4; ++n)
      bf[n] = *(const short8*)&Bs[(wc * 64 + n * 16 + row16) * 32 + kofs];
#pragma unroll
    for (int m = 0; m < 4; ++m)
#pragma unroll
      for (int n = 0; n < 4; ++n)
        acc[m][n] = __builtin_amdgcn_mfma_f32_16x16x32_bf16(af[m], bf[n], acc[m][n], 0, 0, 0);
    __syncthreads();
  }

  float fs = 0.f;
#pragma unroll
  for (int m = 0; m < 4; ++m)
#pragma unroll
    for (int n = 0; n < 4; ++n)
#pragma unroll
      for (int q = 0; q < 4; ++q) fs += acc[m][n][q] * acc[m][n][q];
#pragma unroll
  for (int off = 32; off; off >>= 1) fs += __shfl_down(fs, off);
  if (lane == 0) wred[wid] = fs;
  __syncthreads();
  if (tid == 0)
    frobp[by * 8 + bx] = (double)wred[0] + (double)wred[1] + (double)wred[2] + (double)wred[3];
}

// ---------------------------------------------------------------------------
// K5: final fp64 reduction + scalar math.
// ---------------------------------------------------------------------------
__global__ void __launch_bounds__(256) kfinal(const double* __restrict__ rowp,
                                              const double* __restrict__ cssp,
                                              const int* __restrict__ cntp,
                                              const double* __restrict__ frobp,
                                              float* __restrict__ out) {
  __shared__ double red[256];
  const int tid = threadIdx.x;
  double ls = rowp[2 * tid], lq = rowp[2 * tid + 1];
  double lcss = 0.0, lcnn = 0.0, lfr = 0.0;
  for (int c = tid; c < N_CLS; c += 256) {
    lcss += cssp[c];
    const double nc = (double)cntp[c];
    lcnn += nc * nc;
  }
  if (tid < 64) lfr = frobp[tid];

  double vals[5] = {ls, lq, lcss, lcnn, lfr};
  double res[5];
  for (int v = 0; v < 5; ++v) {
    red[tid] = vals[v];
    __syncthreads();
    for (int s = 128; s; s >>= 1) {
      if (tid < s) red[tid] += red[tid + s];
      __syncthreads();
    }
    res[v] = red[0];
    __syncthreads();
  }
  if (tid == 0) {
    const double sumsq = res[0], sumq = res[1], css = res[2], cnn = res[3], frob = res[4];
    const double S1 = 0.5 * (css - sumsq);
    const double S2 = 0.5 * (cnn - (double)N_ROWS);
    const double S3 = 0.5 * (frob - sumq);
    out[0] = (float)(-(S1 / (S2 * sqrt(S3))));
  }
}

extern "C" void kernel_launch(void* const* d_in, const int* in_sizes, int n_in,
                              void* d_out, int out_size, void* d_ws, size_t ws_size,
                              hipStream_t stream) {
  const float* A = (const float*)d_in[0];
  const int* target = (const int*)d_in[1];
  float* out = (float*)d_out;

  char* ws = (char*)d_ws;
  short* At   = (short*)ws;                                    // 1024*4096*2 = 8,388,608 B
  double* rowp = (double*)(ws + 8388608);                      // 256*2 doubles = 4096 B
  double* cssp = (double*)(ws + 8388608 + 4096);               // 1000 doubles = 8000 B
  int*    cntp = (int*)  (ws + 8388608 + 4096 + 8000);         // 1000 ints    = 4000 B (pad 4096)
  double* frobp= (double*)(ws + 8388608 + 4096 + 8000 + 4096); // 64 doubles   = 512 B

  ktrans<<<dim3(64, 16), 256, 0, stream>>>(A, At);
  krow<<<64, 256, 0, stream>>>(A, rowp);
  kclass<<<N_CLS, 256, 0, stream>>>(A, target, cssp, cntp);
  kgemmfrob<<<dim3(8, 8), 256, 0, stream>>>(At, frobp);
  kfinal<<<1, 256, 0, stream>>>(rowp, cssp, cntp, frobp, out);
}

// Round 2
// 51.482 us; speedup vs baseline: 2.4644x; 2.4644x over previous
//
#include <hip/hip_runtime.h>
#include <hip/hip_bf16.h>

// AlignmentLoss: loss = -(sum(tril(G,-1)*eq) / (sum(tril(eq,-1)) * ||tril(G,-1)||_F))
// with G = A A^T, A: 4096x1024 fp32, target: 4096 int32 (classes < 1000).
//
//   S1 = 0.5*(sum_c ||s_c||^2 - sum_i ||a_i||^2)   (exact fp32/fp64 path)
//   S2 = 0.5*(sum_c n_c^2 - N)
//   S3 = sum_{i>j} g_ij^2  -- computed DIRECTLY on lower-triangle 128x128
//        tiles of G = A A^T in bf16 MFMA (K=1024 along A's natural layout;
//        no transpose, no C materialization, no cancellation).
//   loss = -S1 / (S2 * sqrt(S3))

typedef __attribute__((ext_vector_type(8))) short short8;
typedef __attribute__((ext_vector_type(4))) float f32x4;

#define N_ROWS 4096
#define D_DIM  1024
#define N_CLS  1000
#define NTILE  32          // 4096 / 128 block-rows
#define NBLK   528         // NTILE*(NTILE+1)/2 lower-triangle tiles

__device__ __forceinline__ unsigned short f2bf(float f) {
  unsigned u = __float_as_uint(f);
  u += 0x7fffu + ((u >> 16) & 1u);   // round-to-nearest-even
  return (unsigned short)(u >> 16);
}

__device__ __forceinline__ void gload16(const short* g, const char* l) {
  __builtin_amdgcn_global_load_lds(
      (const __attribute__((address_space(1))) unsigned*)g,
      (__attribute__((address_space(3))) unsigned*)(void*)l, 16, 0, 0);
}

// ---------------------------------------------------------------------------
// kconvrow: A fp32 -> Ab bf16 (same layout, no transpose) + per-block fp64
// partial of sum_i ||a_i||^2.  512 blocks x 256 thr; wave handles 2 rows.
// ---------------------------------------------------------------------------
__global__ void __launch_bounds__(256) kconvrow(const float* __restrict__ A,
                                                short* __restrict__ Ab,
                                                double* __restrict__ rowp) {
  __shared__ double wr2[4];
  const int tid = threadIdx.x, lane = tid & 63, w = tid >> 6;
  const int row0 = blockIdx.x * 8;
  double ls = 0.0;
#pragma unroll
  for (int rr = 0; rr < 2; ++rr) {
    const int i = row0 + w * 2 + rr;
    const float4* src = (const float4*)(A + (size_t)i * D_DIM);
    short4* dst = (short4*)(Ab + (size_t)i * D_DIM);
    float s = 0.f;
#pragma unroll
    for (int c = 0; c < 4; ++c) {
      const float4 v = src[lane + c * 64];
      s += v.x * v.x + v.y * v.y + v.z * v.z + v.w * v.w;
      short4 o;
      o.x = (short)f2bf(v.x); o.y = (short)f2bf(v.y);
      o.z = (short)f2bf(v.z); o.w = (short)f2bf(v.w);
      dst[lane + c * 64] = o;
    }
#pragma unroll
    for (int off = 32; off; off >>= 1) s += __shfl_down(s, off);
    if (lane == 0) ls += (double)s;
  }
  if (lane == 0) wr2[w] = ls;
  __syncthreads();
  if (tid == 0) rowp[blockIdx.x] = wr2[0] + wr2[1] + wr2[2] + wr2[3];
}

// ---------------------------------------------------------------------------
// kclass: block per class; LDS list of matching rows; s_c in registers
// (thread owns 4 dims); emits ||s_c||^2 (fp64) and n_c.  Exact fp32 path.
// ---------------------------------------------------------------------------
__global__ void __launch_bounds__(256) kclass(const float* __restrict__ A,
                                              const int* __restrict__ target,
                                              double* __restrict__ cssp,
                                              int* __restrict__ cntp) {
  __shared__ int list[N_ROWS];
  __shared__ int lcnt;
  __shared__ float wred[4];
  const int c = blockIdx.x, tid = threadIdx.x;
  if (tid == 0) lcnt = 0;
  __syncthreads();
  for (int j = tid; j < N_ROWS; j += 256)
    if (target[j] == c) { int p = atomicAdd(&lcnt, 1); list[p] = j; }
  __syncthreads();
  const int n = lcnt;
  float4 acc = make_float4(0.f, 0.f, 0.f, 0.f);
  for (int m = 0; m < n; ++m) {
    const float4 v = *(const float4*)(A + (size_t)list[m] * D_DIM + tid * 4);
    acc.x += v.x; acc.y += v.y; acc.z += v.z; acc.w += v.w;
  }
  float s = acc.x * acc.x + acc.y * acc.y + acc.z * acc.z + acc.w * acc.w;
#pragma unroll
  for (int off = 32; off; off >>= 1) s += __shfl_down(s, off);
  const int lane = tid & 63, wid = tid >> 6;
  if (lane == 0) wred[wid] = s;
  __syncthreads();
  if (tid == 0) {
    cssp[c] = (double)(wred[0] + wred[1] + wred[2] + wred[3]);
    cntp[c] = n;
  }
}

// ---------------------------------------------------------------------------
// kfrob: lower-triangle 128x128 tiles of G = Ab * Ab^T (K=1024, bf16 MFMA),
// fused masked-Frobenius reduce.  Grid NBLK=528.  m97 structure: BK=32,
// global_load_lds width 16, linear LDS [128][32] shorts, 4 waves (2x2),
// 16x16x32 MFMA, 16 MFMA/wave/K-step.
// Tile value is transpose-safe: G symmetric, mask (r>c vs c>r) symmetric.
// ---------------------------------------------------------------------------
__global__ void __launch_bounds__(256) kfrob(const short* __restrict__ Ab,
                                             double* __restrict__ frobp) {
  __shared__ __align__(16) short As[128 * 32];   // 8 KB
  __shared__ __align__(16) short Bs[128 * 32];   // 8 KB
  __shared__ double wred[4];
  const int tid = threadIdx.x, lane = tid & 63, w = tid >> 6;

  // decode lower-triangle pair: b = bi*(bi+1)/2 + bj, bj <= bi
  const int b = blockIdx.x;
  int bi = (int)((sqrtf(8.f * (float)b + 1.f) - 1.f) * 0.5f);
  while ((bi + 1) * (bi + 2) / 2 <= b) ++bi;
  while (bi * (bi + 1) / 2 > b) --bi;
  const int bj = b - bi * (bi + 1) / 2;
  const bool diag = (bi == bj);

  const short* Pa = Ab + (size_t)(bi * 128) * D_DIM;
  const short* Pb = Ab + (size_t)(bj * 128) * D_DIM;

  f32x4 acc[4][4];
#pragma unroll
  for (int m = 0; m < 4; ++m)
#pragma unroll
    for (int n = 0; n < 4; ++n) acc[m][n] = (f32x4){0.f, 0.f, 0.f, 0.f};

  const int wr = w >> 1, wc = w & 1;
  const int row16 = lane & 15, ko = (lane >> 4) * 8;
  const int sr = tid >> 2, sc = tid & 3;          // staging row/chunk (per issue)

  for (int k0 = 0; k0 < D_DIM; k0 += 32) {
#pragma unroll
    for (int s = 0; s < 2; ++s) {
      const int r = s * 64 + sr;
      const size_t gofs = (size_t)r * D_DIM + k0 + sc * 8;
      const int lofs = s * 4096 + w * 1024;       // wave-uniform LDS byte base
      gload16(Pa + gofs, (const char*)As + lofs);
      gload16(Pb + gofs, (const char*)Bs + lofs);
    }
    __syncthreads();
    short8 af[4], bf[4];
#pragma unroll
    for (int m = 0; m < 4; ++m)
      af[m] = *(const short8*)&As[(wr * 64 + m * 16 + row16) * 32 + ko];
#pragma unroll
    for (int n = 0; n < 4; ++n)
      bf[n] = *(const short8*)&Bs[(wc * 64 + n * 16 + row16) * 32 + ko];
#pragma unroll
    for (int m = 0; m < 4; ++m)
#pragma unroll
      for (int n = 0; n < 4; ++n)
        acc[m][n] = __builtin_amdgcn_mfma_f32_16x16x32_bf16(af[m], bf[n], acc[m][n], 0, 0, 0);
    __syncthreads();
  }

  float fs = 0.f;
  if (!diag) {
#pragma unroll
    for (int m = 0; m < 4; ++m)
#pragma unroll
      for (int n = 0; n < 4; ++n)
#pragma unroll
        for (int q = 0; q < 4; ++q) fs += acc[m][n][q] * acc[m][n][q];
  } else {
    const int rbase = (lane >> 4) * 4, cbase = lane & 15;
#pragma unroll
    for (int m = 0; m < 4; ++m)
#pragma unroll
      for (int n = 0; n < 4; ++n)
#pragma unroll
        for (int q = 0; q < 4; ++q) {
          const int rl = wr * 64 + m * 16 + rbase + q;
          const int cl = wc * 64 + n * 16 + cbase;
          if (rl > cl) fs += acc[m][n][q] * acc[m][n][q];
        }
  }
#pragma unroll
  for (int off = 32; off; off >>= 1) fs += __shfl_down(fs, off);
  if (lane == 0) wred[w] = (double)fs;
  __syncthreads();
  if (tid == 0)
    frobp[b] = wred[0] + wred[1] + wred[2] + wred[3];
}

// ---------------------------------------------------------------------------
// kfinal: fp64 reduce + scalar math.
// ---------------------------------------------------------------------------
__global__ void __launch_bounds__(256) kfinal(const double* __restrict__ rowp,
                                              const double* __restrict__ cssp,
                                              const int* __restrict__ cntp,
                                              const double* __restrict__ frobp,
                                              float* __restrict__ out) {
  __shared__ double red[256];
  const int tid = threadIdx.x;
  double lsum = rowp[tid] + rowp[tid + 256];
  double lcss = 0.0, lcnn = 0.0, lfr = 0.0;
  for (int c = tid; c < N_CLS; c += 256) {
    lcss += cssp[c];
    const double nc = (double)cntp[c];
    lcnn += nc * nc;
  }
  for (int c = tid; c < NBLK; c += 256) lfr += frobp[c];

  double vals[4] = {lsum, lcss, lcnn, lfr};
  double res[4];
  for (int v = 0; v < 4; ++v) {
    red[tid] = vals[v];
    __syncthreads();
    for (int s = 128; s; s >>= 1) {
      if (tid < s) red[tid] += red[tid + s];
      __syncthreads();
    }
    res[v] = red[0];
    __syncthreads();
  }
  if (tid == 0) {
    const double sumr = res[0], css = res[1], cnn = res[2], frob = res[3];
    const double S1 = 0.5 * (css - sumr);
    const double S2 = 0.5 * (cnn - (double)N_ROWS);
    const double S3 = frob;
    out[0] = (float)(-(S1 / (S2 * sqrt(S3))));
  }
}

extern "C" void kernel_launch(void* const* d_in, const int* in_sizes, int n_in,
                              void* d_out, int out_size, void* d_ws, size_t ws_size,
                              hipStream_t stream) {
  const float* A = (const float*)d_in[0];
  const int* target = (const int*)d_in[1];
  float* out = (float*)d_out;

  char* ws = (char*)d_ws;
  short*  Ab    = (short*)ws;                                   // 8,388,608 B
  double* rowp  = (double*)(ws + 8388608);                      // 512 doubles
  double* cssp  = (double*)(ws + 8388608 + 4096);               // 1000 doubles
  int*    cntp  = (int*)   (ws + 8388608 + 4096 + 8000);        // 1000 ints (pad 4096)
  double* frobp = (double*)(ws + 8388608 + 4096 + 8000 + 4096); // 528 doubles

  kconvrow<<<512, 256, 0, stream>>>(A, Ab, rowp);
  kclass<<<N_CLS, 256, 0, stream>>>(A, target, cssp, cntp);
  kfrob<<<NBLK, 256, 0, stream>>>(Ab, frobp);
  kfinal<<<1, 256, 0, stream>>>(rowp, cssp, cntp, frobp, out);
}